// Round 2
// baseline (4778.939 us; speedup 1.0000x reference)
//
#include <hip/hip_runtime.h>
#include <hip/hip_bf16.h>

// Problem constants (from reference setup_inputs)
#define NNODES 100000
#define NEDGES 300000
#define FIN 128
#define HDIM 256
#define NLAYERS 3

// ---------------------------------------------------------------------------
// Tiled GEMM: C[M,P] = act(A[M,K] @ B[K,P] + bias)   — all fp32
// Block = 256 threads (16x16), 64x64 output tile, 4x4 per thread, K-chunks 16.
// ---------------------------------------------------------------------------
template <bool BIAS, bool RELU>
__global__ __launch_bounds__(256) void gemm_k(const float* __restrict__ A,
                                              const float* __restrict__ B,
                                              const float* __restrict__ bias,
                                              float* __restrict__ C,
                                              int M, int P, int K) {
    __shared__ float As[64][17];
    __shared__ float Bs[16][65];
    const int tx = threadIdx.x & 15;
    const int ty = threadIdx.x >> 4;
    const int row0 = blockIdx.y * 64;
    const int col0 = blockIdx.x * 64;

    float acc[4][4] = {};

    for (int k0 = 0; k0 < K; k0 += 16) {
        // Stage A tile: 64 rows x 16 k  (K is a multiple of 16)
        for (int i = threadIdx.x; i < 64 * 16; i += 256) {
            int r = i >> 4, c = i & 15;
            int gr = row0 + r;
            float v = 0.0f;
            if (gr < M) v = A[(size_t)gr * K + (k0 + c)];
            As[r][c] = v;
        }
        // Stage B tile: 16 k x 64 cols (P=256, col0+c always in range)
        for (int i = threadIdx.x; i < 16 * 64; i += 256) {
            int r = i >> 6, c = i & 63;
            Bs[r][c] = B[(size_t)(k0 + r) * P + (col0 + c)];
        }
        __syncthreads();
#pragma unroll
        for (int kk = 0; kk < 16; ++kk) {
            float a[4], b[4];
#pragma unroll
            for (int i = 0; i < 4; ++i) a[i] = As[ty * 4 + i][kk];
#pragma unroll
            for (int j = 0; j < 4; ++j) b[j] = Bs[kk][tx * 4 + j];
#pragma unroll
            for (int i = 0; i < 4; ++i)
#pragma unroll
                for (int j = 0; j < 4; ++j) acc[i][j] += a[i] * b[j];
        }
        __syncthreads();
    }

#pragma unroll
    for (int i = 0; i < 4; ++i) {
        int gr = row0 + ty * 4 + i;
        if (gr >= M) continue;
#pragma unroll
        for (int j = 0; j < 4; ++j) {
            int gc = col0 + tx * 4 + j;
            float v = acc[i][j];
            if (BIAS) v += bias[gc];
            if (RELU) v = fmaxf(v, 0.0f);
            C[(size_t)gr * P + gc] = v;
        }
    }
}

// ---------------------------------------------------------------------------
// Zero a u32 buffer (avoid hipMemsetAsync semantics questions under capture)
// ---------------------------------------------------------------------------
__global__ void zero_k(unsigned* __restrict__ p, int n) {
    int i = blockIdx.x * blockDim.x + threadIdx.x;
    if (i < n) p[i] = 0u;
}

// ---------------------------------------------------------------------------
// Degree count: one atomic inc per edge on dst
// ---------------------------------------------------------------------------
__global__ void count_k(const int* __restrict__ dst, unsigned* __restrict__ cnt, int E) {
    int e = blockIdx.x * blockDim.x + threadIdx.x;
    if (e < E) atomicAdd(&cnt[dst[e]], 1u);
}

__global__ void dinv_k(const unsigned* __restrict__ cnt, float* __restrict__ dinv, int N) {
    int i = blockIdx.x * blockDim.x + threadIdx.x;
    if (i < N) dinv[i] = 1.0f / sqrtf((float)(cnt[i] + 1u));  // +1 = self loop
}

// ---------------------------------------------------------------------------
// acc[i,:] = m[i,:] * dinv[i]^2   (self-loop contribution, also inits acc)
// ---------------------------------------------------------------------------
__global__ void self_init_k(const float* __restrict__ m, const float* __restrict__ dinv,
                            float* __restrict__ acc) {
    int i = blockIdx.x * blockDim.x + threadIdx.x;  // over N*H = 25.6M
    int row = i >> 8;                                // H = 256
    float d = dinv[row];
    acc[i] = m[i] * (d * d);
}

// ---------------------------------------------------------------------------
// Edge scatter: one wave (64 lanes) per edge; float4 per lane (256 cols),
// 4 global fp32 atomics per lane.
// ---------------------------------------------------------------------------
__global__ __launch_bounds__(256) void scatter_k(const int* __restrict__ src,
                                                 const int* __restrict__ dst,
                                                 const float* __restrict__ dinv,
                                                 const float* __restrict__ m,
                                                 float* __restrict__ acc, int E) {
    int e = blockIdx.x * 4 + (threadIdx.x >> 6);
    int lane = threadIdx.x & 63;
    if (e >= E) return;
    int s = src[e];
    int d = dst[e];
    float w = dinv[s] * dinv[d];
    const float4* ms = (const float4*)(m + (size_t)s * HDIM);
    float* ad = acc + (size_t)d * HDIM;
    float4 v = ms[lane];
    atomicAdd(&ad[lane * 4 + 0], v.x * w);
    atomicAdd(&ad[lane * 4 + 1], v.y * w);
    atomicAdd(&ad[lane * 4 + 2], v.z * w);
    atomicAdd(&ad[lane * 4 + 3], v.w * w);
}

// ---------------------------------------------------------------------------
// h = relu(acc + bias), fp32 (in-place or to d_out on last layer)
// ---------------------------------------------------------------------------
__global__ void bias_relu_k(const float* __restrict__ acc, const float* __restrict__ bias,
                            float* __restrict__ out) {
    int i = blockIdx.x * blockDim.x + threadIdx.x;  // over N*H
    float v = acc[i] + bias[i & 255];
    out[i] = fmaxf(v, 0.0f);
}

extern "C" void kernel_launch(void* const* d_in, const int* in_sizes, int n_in,
                              void* d_out, int out_size, void* d_ws, size_t ws_size,
                              hipStream_t stream) {
    const float* x  = (const float*)d_in[0];
    const int* ei   = (const int*)d_in[1];
    const float* w1 = (const float*)d_in[2];
    const float* b1 = (const float*)d_in[3];
    const float* w2 = (const float*)d_in[4];
    const float* b2 = (const float*)d_in[5];
    const float* gw = (const float*)d_in[6];
    const float* gb = (const float*)d_in[7];

    const int N = NNODES, E = NEDGES;
    const int* src = ei;          // edge_index[0]
    const int* dst = ei + E;      // edge_index[1]

    // Workspace layout
    char* ws = (char*)d_ws;
    const size_t HBUF = (size_t)N * HDIM * sizeof(float);  // 102,400,000 B
    float* buf0 = (float*)ws;                   // m / encoder hidden
    float* buf1 = (float*)(ws + HBUF);          // h / acc
    unsigned* cnt = (unsigned*)(ws + 2 * HBUF); // N u32
    float* dinv = (float*)(ws + 2 * HBUF + (size_t)N * 4);

    const int NH = N * HDIM;  // 25.6M
    const dim3 gemm_grid(HDIM / 64, (N + 63) / 64);  // (4, 1563)

    // Degree / normalization
    zero_k<<<(N + 255) / 256, 256, 0, stream>>>(cnt, N);
    count_k<<<(E + 255) / 256, 256, 0, stream>>>(dst, cnt, E);
    dinv_k<<<(N + 255) / 256, 256, 0, stream>>>(cnt, dinv, N);

    // Encoder: buf0 = relu(x@W1+b1); buf1 = buf0@W2+b2
    gemm_k<true, true><<<gemm_grid, 256, 0, stream>>>(x, w1, b1, buf0, N, HDIM, FIN);
    gemm_k<true, false><<<gemm_grid, 256, 0, stream>>>(buf0, w2, b2, buf1, N, HDIM, HDIM);

    // GCN layers: h lives in buf1; m in buf0; acc overwrites buf1 after GEMM
    for (int l = 0; l < NLAYERS; ++l) {
        const float* wl = gw + (size_t)l * HDIM * HDIM;
        const float* bl = gb + (size_t)l * HDIM;
        gemm_k<false, false><<<gemm_grid, 256, 0, stream>>>(buf1, wl, nullptr, buf0, N, HDIM, HDIM);
        self_init_k<<<NH / 256, 256, 0, stream>>>(buf0, dinv, buf1);
        scatter_k<<<(E + 3) / 4, 256, 0, stream>>>(src, dst, dinv, buf0, buf1, E);
        bias_relu_k<<<NH / 256, 256, 0, stream>>>(buf1, bl, (l < NLAYERS - 1) ? buf1 : (float*)d_out);
    }
}

// Round 3
// 1722.302 us; speedup vs baseline: 2.7747x; 2.7747x over previous
//
#include <hip/hip_runtime.h>
#include <hip/hip_bf16.h>

// Problem constants (from reference setup_inputs)
#define NNODES 100000
#define NEDGES 300000
#define FIN 128
#define HDIM 256
#define NLAYERS 3

// ---------------------------------------------------------------------------
// Tiled GEMM: C[M,P] = act(A[M,K] @ B[K,P] + bias)   — all fp32
// Block = 256 threads (16x16), 64x64 output tile, 4x4 per thread, K-chunks 16.
// ---------------------------------------------------------------------------
template <bool BIAS, bool RELU>
__global__ __launch_bounds__(256) void gemm_k(const float* __restrict__ A,
                                              const float* __restrict__ B,
                                              const float* __restrict__ bias,
                                              float* __restrict__ C,
                                              int M, int P, int K) {
    __shared__ float As[64][17];
    __shared__ float Bs[16][65];
    const int tx = threadIdx.x & 15;
    const int ty = threadIdx.x >> 4;
    const int row0 = blockIdx.y * 64;
    const int col0 = blockIdx.x * 64;

    float acc[4][4] = {};

    for (int k0 = 0; k0 < K; k0 += 16) {
        for (int i = threadIdx.x; i < 64 * 16; i += 256) {
            int r = i >> 4, c = i & 15;
            int gr = row0 + r;
            float v = 0.0f;
            if (gr < M) v = A[(size_t)gr * K + (k0 + c)];
            As[r][c] = v;
        }
        for (int i = threadIdx.x; i < 16 * 64; i += 256) {
            int r = i >> 6, c = i & 63;
            Bs[r][c] = B[(size_t)(k0 + r) * P + (col0 + c)];
        }
        __syncthreads();
#pragma unroll
        for (int kk = 0; kk < 16; ++kk) {
            float a[4], b[4];
#pragma unroll
            for (int i = 0; i < 4; ++i) a[i] = As[ty * 4 + i][kk];
#pragma unroll
            for (int j = 0; j < 4; ++j) b[j] = Bs[kk][tx * 4 + j];
#pragma unroll
            for (int i = 0; i < 4; ++i)
#pragma unroll
                for (int j = 0; j < 4; ++j) acc[i][j] += a[i] * b[j];
        }
        __syncthreads();
    }

#pragma unroll
    for (int i = 0; i < 4; ++i) {
        int gr = row0 + ty * 4 + i;
        if (gr >= M) continue;
#pragma unroll
        for (int j = 0; j < 4; ++j) {
            int gc = col0 + tx * 4 + j;
            float v = acc[i][j];
            if (BIAS) v += bias[gc];
            if (RELU) v = fmaxf(v, 0.0f);
            C[(size_t)gr * P + gc] = v;
        }
    }
}

// ---------------------------------------------------------------------------
// Small utility kernels
// ---------------------------------------------------------------------------
__global__ void zero_k(unsigned* __restrict__ p, int n) {
    int i = blockIdx.x * blockDim.x + threadIdx.x;
    if (i < n) p[i] = 0u;
}

__global__ void count_k(const int* __restrict__ dst, unsigned* __restrict__ cnt, int E) {
    int e = blockIdx.x * blockDim.x + threadIdx.x;
    if (e < E) atomicAdd(&cnt[dst[e]], 1u);
}

__global__ void dinv_k(const unsigned* __restrict__ cnt, float* __restrict__ dinv, int N) {
    int i = blockIdx.x * blockDim.x + threadIdx.x;
    if (i < N) dinv[i] = 1.0f / sqrtf((float)(cnt[i] + 1u));  // +1 = self loop
}

// ---------------------------------------------------------------------------
// Exclusive prefix scan of cnt[N] -> rs[N] (+ rs[N] = E), 3-kernel hierarchy.
// ---------------------------------------------------------------------------
__global__ __launch_bounds__(256) void scan1_k(const unsigned* __restrict__ cnt,
                                               int* __restrict__ rs,
                                               unsigned* __restrict__ blocksum, int N) {
    __shared__ unsigned tmp[256];
    int tid = threadIdx.x;
    int gid = blockIdx.x * 256 + tid;
    unsigned v = (gid < N) ? cnt[gid] : 0u;
    tmp[tid] = v;
    __syncthreads();
#pragma unroll
    for (int off = 1; off < 256; off <<= 1) {
        unsigned t = (tid >= off) ? tmp[tid - off] : 0u;
        __syncthreads();
        tmp[tid] += t;
        __syncthreads();
    }
    if (gid < N) rs[gid] = (int)(tmp[tid] - v);  // exclusive within block
    if (tid == 255) blocksum[blockIdx.x] = tmp[tid];
}

__global__ __launch_bounds__(512) void scan2_k(unsigned* __restrict__ blocksum, int nb) {
    __shared__ unsigned tmp[512];
    int tid = threadIdx.x;
    unsigned v = (tid < nb) ? blocksum[tid] : 0u;
    tmp[tid] = v;
    __syncthreads();
#pragma unroll
    for (int off = 1; off < 512; off <<= 1) {
        unsigned t = (tid >= off) ? tmp[tid - off] : 0u;
        __syncthreads();
        tmp[tid] += t;
        __syncthreads();
    }
    if (tid < nb) blocksum[tid] = tmp[tid] - v;  // exclusive
}

__global__ void scan3_k(int* __restrict__ rs, const unsigned* __restrict__ blocksum, int N, int E) {
    int gid = blockIdx.x * blockDim.x + threadIdx.x;
    if (gid < N) rs[gid] += (int)blocksum[gid >> 8];
    if (gid == 0) rs[N] = E;
}

// ---------------------------------------------------------------------------
// Fill CSR: for each edge, place src + precomputed weight at its slot.
// ---------------------------------------------------------------------------
__global__ void fill_k(const int* __restrict__ src, const int* __restrict__ dst,
                       const int* __restrict__ rs, unsigned* __restrict__ cursor,
                       const float* __restrict__ dinv,
                       int* __restrict__ srcs, float* __restrict__ ww, int E) {
    int e = blockIdx.x * blockDim.x + threadIdx.x;
    if (e >= E) return;
    int s = src[e], d = dst[e];
    int pos = rs[d] + (int)atomicAdd(&cursor[d], 1u);
    srcs[pos] = s;
    ww[pos] = dinv[s] * dinv[d];
}

// ---------------------------------------------------------------------------
// CSR gather-aggregate, fused self-loop + bias + ReLU.
// One wave (64 lanes) per node; float4 per lane covers 256 cols.
// ---------------------------------------------------------------------------
__global__ __launch_bounds__(256) void gather_k(const int* __restrict__ rs,
                                                const int* __restrict__ srcs,
                                                const float* __restrict__ ww,
                                                const float* __restrict__ dinv,
                                                const float* __restrict__ m,
                                                const float* __restrict__ bias,
                                                float* __restrict__ out, int N) {
    int node = blockIdx.x * 4 + (threadIdx.x >> 6);
    int lane = threadIdx.x & 63;
    if (node >= N) return;
    int beg = rs[node], end = rs[node + 1];
    float d = dinv[node];
    float w0 = d * d;  // self-loop weight
    float4 acc = ((const float4*)(m + (size_t)node * HDIM))[lane];
    acc.x *= w0; acc.y *= w0; acc.z *= w0; acc.w *= w0;
    for (int e = beg; e < end; ++e) {
        int s = srcs[e];
        float w = ww[e];
        float4 v = ((const float4*)(m + (size_t)s * HDIM))[lane];
        acc.x += v.x * w;
        acc.y += v.y * w;
        acc.z += v.z * w;
        acc.w += v.w * w;
    }
    float4 b = ((const float4*)bias)[lane];
    acc.x = fmaxf(acc.x + b.x, 0.0f);
    acc.y = fmaxf(acc.y + b.y, 0.0f);
    acc.z = fmaxf(acc.z + b.z, 0.0f);
    acc.w = fmaxf(acc.w + b.w, 0.0f);
    ((float4*)(out + (size_t)node * HDIM))[lane] = acc;
}

extern "C" void kernel_launch(void* const* d_in, const int* in_sizes, int n_in,
                              void* d_out, int out_size, void* d_ws, size_t ws_size,
                              hipStream_t stream) {
    const float* x  = (const float*)d_in[0];
    const int* ei   = (const int*)d_in[1];
    const float* w1 = (const float*)d_in[2];
    const float* b1 = (const float*)d_in[3];
    const float* w2 = (const float*)d_in[4];
    const float* b2 = (const float*)d_in[5];
    const float* gw = (const float*)d_in[6];
    const float* gb = (const float*)d_in[7];

    const int N = NNODES, E = NEDGES;
    const int* src = ei;          // edge_index[0]
    const int* dst = ei + E;      // edge_index[1]

    // Workspace layout (~106 MB; d_out doubles as the persistent h buffer)
    char* ws = (char*)d_ws;
    const size_t HBUF = (size_t)N * HDIM * sizeof(float);  // 102,400,000 B
    float* bufm = (float*)ws;                          // m / encoder hidden
    char* p = ws + HBUF;
    unsigned* cnt = (unsigned*)p;      p += (size_t)N * 4;       // degree, later cursor
    float* dinv = (float*)p;           p += (size_t)N * 4;
    int* rs = (int*)p;                 p += (size_t)(N + 1) * 4; // row_start
    unsigned* blocksum = (unsigned*)p; p += 512 * 4;
    int* srcs = (int*)p;               p += (size_t)E * 4;       // CSR src
    float* wwt = (float*)p;            p += (size_t)E * 4;       // CSR weight
    float* h = (float*)d_out;

    const int nb = (N + 255) / 256;  // 391 scan blocks
    const dim3 gemm_grid(HDIM / 64, (N + 63) / 64);  // (4, 1563)

    // ---- CSR build ----
    zero_k<<<nb, 256, 0, stream>>>(cnt, N);
    count_k<<<(E + 255) / 256, 256, 0, stream>>>(dst, cnt, E);
    dinv_k<<<nb, 256, 0, stream>>>(cnt, dinv, N);
    scan1_k<<<nb, 256, 0, stream>>>(cnt, rs, blocksum, N);
    scan2_k<<<1, 512, 0, stream>>>(blocksum, nb);
    scan3_k<<<nb + 1, 256, 0, stream>>>(rs, blocksum, N, E);
    zero_k<<<nb, 256, 0, stream>>>(cnt, N);  // reuse cnt as cursor
    fill_k<<<(E + 255) / 256, 256, 0, stream>>>(src, dst, rs, cnt, dinv, srcs, wwt, E);

    // ---- Encoder: bufm = relu(x@W1+b1); h = bufm@W2+b2 ----
    gemm_k<true, true><<<gemm_grid, 256, 0, stream>>>(x, w1, b1, bufm, N, HDIM, FIN);
    gemm_k<true, false><<<gemm_grid, 256, 0, stream>>>(bufm, w2, b2, h, N, HDIM, HDIM);

    // ---- GCN layers: m = h@Wl; h = relu(Â m + bl) ----
    for (int l = 0; l < NLAYERS; ++l) {
        const float* wl = gw + (size_t)l * HDIM * HDIM;
        const float* bl = gb + (size_t)l * HDIM;
        gemm_k<false, false><<<gemm_grid, 256, 0, stream>>>(h, wl, nullptr, bufm, N, HDIM, HDIM);
        gather_k<<<(N + 3) / 4, 256, 0, stream>>>(rs, srcs, wwt, dinv, bufm, bl, h, N);
    }
}

// Round 4
// 604.658 us; speedup vs baseline: 7.9035x; 2.8484x over previous
//
#include <hip/hip_runtime.h>
#include <hip/hip_bf16.h>

// Problem constants
#define NNODES 100000
#define NEDGES 300000
#define FIN 128
#define HDIM 256
#define NLAYERS 3
#define MPAD 100096  // 391 * 256 (row padding so A-frag loads never fault)

typedef float f32x4 __attribute__((ext_vector_type(4)));
typedef short bf16x8 __attribute__((ext_vector_type(8)));

__device__ inline float bf2f(unsigned short u) {
    union { unsigned int i; float f; } v;
    v.i = ((unsigned int)u) << 16;
    return v.f;
}
__device__ inline unsigned short f2bf(float f) {  // RNE
    union { float f; unsigned int i; } v;
    v.f = f;
    return (unsigned short)((v.i + 0x7fffu + ((v.i >> 16) & 1u)) >> 16);
}

// ---------------------------------------------------------------------------
// MFMA GEMM: C[M,256] = act(A[M,K] @ B[K,256] + bias)
// A: bf16 [MPAD][K]. Bt: bf16 [256][K] (pre-transposed). bias fp32.
// Block = 256 thr = 4 waves; tile 256 rows x 64 cols; wave = 64x64 via
// 4x4 of 16x16x32 MFMA. B col-block resident in LDS (staged once, padded
// stride K+8 -> conflict-free frag reads). A-frags straight from global
// (16B/lane, 16 fully-used 64B lines per instr). NO barrier in K-loop.
// ---------------------------------------------------------------------------
template <bool BIAS, bool RELU, bool OUTF32>
__global__ __launch_bounds__(256) void gemm_mfma_k(
    const unsigned short* __restrict__ A, const unsigned short* __restrict__ Bt,
    const float* __restrict__ bias, void* __restrict__ C, int M, int K) {
    __shared__ __align__(16) unsigned short Bs[64 * 264];  // max K=256: stride 264
    const int KP = K + 8;
    const int tid = threadIdx.x;
    const int lane = tid & 63;
    const int wid = tid >> 6;
    const int col0 = blockIdx.x * 64;
    const int rowbase = blockIdx.y * 256 + wid * 64;

    // Stage Bt[col0..+64][0..K] -> LDS with padded stride
    const int segs = K / 8;  // 16B segments per column
    for (int i = tid; i < 64 * segs; i += 256) {
        int c = i / segs, s = i % segs;
        const int4* src = (const int4*)(Bt + (size_t)(col0 + c) * K) + s;
        *((int4*)(Bs + c * KP + s * 8)) = *src;
    }
    __syncthreads();

    f32x4 acc[4][4] = {};
    const int r15 = lane & 15;
    const int kq = lane >> 4;  // 0..3

    for (int k0 = 0; k0 < K; k0 += 32) {
        bf16x8 af[4], bfr[4];
#pragma unroll
        for (int i = 0; i < 4; ++i) {
            size_t row = (size_t)(rowbase + i * 16 + r15);
            af[i] = *((const bf16x8*)(A + row * K + k0 + kq * 8));
        }
#pragma unroll
        for (int j = 0; j < 4; ++j)
            bfr[j] = *((const bf16x8*)(Bs + (j * 16 + r15) * KP + k0 + kq * 8));
#pragma unroll
        for (int i = 0; i < 4; ++i)
#pragma unroll
            for (int j = 0; j < 4; ++j)
                acc[i][j] = __builtin_amdgcn_mfma_f32_16x16x32_bf16(af[i], bfr[j], acc[i][j], 0, 0, 0);
    }

    // Epilogue: C/D layout col=lane&15, row=(lane>>4)*4+reg
#pragma unroll
    for (int i = 0; i < 4; ++i) {
#pragma unroll
        for (int reg = 0; reg < 4; ++reg) {
            int row = rowbase + i * 16 + (lane >> 4) * 4 + reg;
            if (row >= M) continue;
#pragma unroll
            for (int j = 0; j < 4; ++j) {
                int col = col0 + j * 16 + (lane & 15);
                float v = acc[i][j][reg];
                if (BIAS) v += bias[col];
                if (RELU) v = fmaxf(v, 0.0f);
                if (OUTF32)
                    ((float*)C)[(size_t)row * HDIM + col] = v;
                else
                    ((unsigned short*)C)[(size_t)row * HDIM + col] = f2bf(v);
            }
        }
    }
}

// ---------------------------------------------------------------------------
// Weight prep: W[nm][K][256] fp32 -> Wt[nm][256][K] bf16 (transpose+convert)
// ---------------------------------------------------------------------------
__global__ void wprep_k(const float* __restrict__ W, unsigned short* __restrict__ Wt,
                        int K, int total) {
    int i = blockIdx.x * blockDim.x + threadIdx.x;
    if (i >= total) return;
    int mat = i / (K * 256);
    int r = i - mat * (K * 256);
    int k = r >> 8, p = r & 255;
    Wt[(size_t)mat * K * 256 + (size_t)p * K + k] = f2bf(W[i]);
}

// x fp32 -> bf16 (vectorized: n must be divisible by 4)
__global__ void xconv_k(const float* __restrict__ x, unsigned short* __restrict__ xb, int n4) {
    int i = blockIdx.x * blockDim.x + threadIdx.x;
    if (i >= n4) return;
    float4 v = ((const float4*)x)[i];
    ushort4 o;
    o.x = f2bf(v.x); o.y = f2bf(v.y); o.z = f2bf(v.z); o.w = f2bf(v.w);
    ((ushort4*)xb)[i] = o;
}

// ---------------------------------------------------------------------------
// Small utility kernels (CSR build)
// ---------------------------------------------------------------------------
__global__ void zero_k(unsigned* __restrict__ p, int n) {
    int i = blockIdx.x * blockDim.x + threadIdx.x;
    if (i < n) p[i] = 0u;
}

__global__ void count_k(const int* __restrict__ dst, unsigned* __restrict__ cnt, int E) {
    int e = blockIdx.x * blockDim.x + threadIdx.x;
    if (e < E) atomicAdd(&cnt[dst[e]], 1u);
}

__global__ void dinv_k(const unsigned* __restrict__ cnt, float* __restrict__ dinv, int N) {
    int i = blockIdx.x * blockDim.x + threadIdx.x;
    if (i < N) dinv[i] = 1.0f / sqrtf((float)(cnt[i] + 1u));  // +1 = self loop
}

__global__ __launch_bounds__(256) void scan1_k(const unsigned* __restrict__ cnt,
                                               int* __restrict__ rs,
                                               unsigned* __restrict__ blocksum, int N) {
    __shared__ unsigned tmp[256];
    int tid = threadIdx.x;
    int gid = blockIdx.x * 256 + tid;
    unsigned v = (gid < N) ? cnt[gid] : 0u;
    tmp[tid] = v;
    __syncthreads();
#pragma unroll
    for (int off = 1; off < 256; off <<= 1) {
        unsigned t = (tid >= off) ? tmp[tid - off] : 0u;
        __syncthreads();
        tmp[tid] += t;
        __syncthreads();
    }
    if (gid < N) rs[gid] = (int)(tmp[tid] - v);
    if (tid == 255) blocksum[blockIdx.x] = tmp[tid];
}

__global__ __launch_bounds__(512) void scan2_k(unsigned* __restrict__ blocksum, int nb) {
    __shared__ unsigned tmp[512];
    int tid = threadIdx.x;
    unsigned v = (tid < nb) ? blocksum[tid] : 0u;
    tmp[tid] = v;
    __syncthreads();
#pragma unroll
    for (int off = 1; off < 512; off <<= 1) {
        unsigned t = (tid >= off) ? tmp[tid - off] : 0u;
        __syncthreads();
        tmp[tid] += t;
        __syncthreads();
    }
    if (tid < nb) blocksum[tid] = tmp[tid] - v;
}

__global__ void scan3_k(int* __restrict__ rs, const unsigned* __restrict__ blocksum, int N, int E) {
    int gid = blockIdx.x * blockDim.x + threadIdx.x;
    if (gid < N) rs[gid] += (int)blocksum[gid >> 8];
    if (gid == 0) rs[N] = E;
}

__global__ void fill_k(const int* __restrict__ src, const int* __restrict__ dst,
                       const int* __restrict__ rs, unsigned* __restrict__ cursor,
                       const float* __restrict__ dinv,
                       int* __restrict__ srcs, float* __restrict__ ww, int E) {
    int e = blockIdx.x * blockDim.x + threadIdx.x;
    if (e >= E) return;
    int s = src[e], d = dst[e];
    int pos = rs[d] + (int)atomicAdd(&cursor[d], 1u);
    srcs[pos] = s;
    ww[pos] = dinv[s] * dinv[d];
}

// ---------------------------------------------------------------------------
// CSR gather-aggregate (bf16 m), fused self-loop + bias + ReLU.
// One wave per node; ushort4 (4 cols) per lane.
// ---------------------------------------------------------------------------
template <bool OUTF32>
__global__ __launch_bounds__(256) void gather_k(const int* __restrict__ rs,
                                                const int* __restrict__ srcs,
                                                const float* __restrict__ ww,
                                                const float* __restrict__ dinv,
                                                const unsigned short* __restrict__ m,
                                                const float* __restrict__ bias,
                                                void* __restrict__ out, int N) {
    int node = blockIdx.x * 4 + (threadIdx.x >> 6);
    int lane = threadIdx.x & 63;
    if (node >= N) return;
    int beg = rs[node], end = rs[node + 1];
    float d = dinv[node];
    float w0 = d * d;
    ushort4 u = ((const ushort4*)(m + (size_t)node * HDIM))[lane];
    float ax = bf2f(u.x) * w0, ay = bf2f(u.y) * w0, az = bf2f(u.z) * w0, aw = bf2f(u.w) * w0;
    for (int e = beg; e < end; ++e) {
        int s = srcs[e];
        float w = ww[e];
        ushort4 v = ((const ushort4*)(m + (size_t)s * HDIM))[lane];
        ax += bf2f(v.x) * w;
        ay += bf2f(v.y) * w;
        az += bf2f(v.z) * w;
        aw += bf2f(v.w) * w;
    }
    float4 b = ((const float4*)bias)[lane];
    ax = fmaxf(ax + b.x, 0.0f);
    ay = fmaxf(ay + b.y, 0.0f);
    az = fmaxf(az + b.z, 0.0f);
    aw = fmaxf(aw + b.w, 0.0f);
    if (OUTF32) {
        float4 o = {ax, ay, az, aw};
        ((float4*)out)[(size_t)node * 64 + lane] = o;
    } else {
        ushort4 o;
        o.x = f2bf(ax); o.y = f2bf(ay); o.z = f2bf(az); o.w = f2bf(aw);
        ((ushort4*)out)[(size_t)node * 64 + lane] = o;
    }
}

extern "C" void kernel_launch(void* const* d_in, const int* in_sizes, int n_in,
                              void* d_out, int out_size, void* d_ws, size_t ws_size,
                              hipStream_t stream) {
    const float* x  = (const float*)d_in[0];
    const int* ei   = (const int*)d_in[1];
    const float* w1 = (const float*)d_in[2];
    const float* b1 = (const float*)d_in[3];
    const float* w2 = (const float*)d_in[4];
    const float* b2 = (const float*)d_in[5];
    const float* gw = (const float*)d_in[6];
    const float* gb = (const float*)d_in[7];

    const int N = NNODES, E = NEDGES;
    const int* src = ei;
    const int* dst = ei + E;

    // Workspace layout (~184 MB)
    char* p = (char*)d_ws;
    unsigned short* xb  = (unsigned short*)p; p += (size_t)MPAD * FIN * 2;   // 25.6 MB
    unsigned short* h1  = (unsigned short*)p; p += (size_t)MPAD * HDIM * 2;  // 51.2 MB
    unsigned short* h   = (unsigned short*)p; p += (size_t)MPAD * HDIM * 2;
    unsigned short* m   = (unsigned short*)p; p += (size_t)MPAD * HDIM * 2;
    unsigned short* w1t = (unsigned short*)p; p += (size_t)FIN * HDIM * 2;
    unsigned short* w2t = (unsigned short*)p; p += (size_t)HDIM * HDIM * 2;
    unsigned short* gwt = (unsigned short*)p; p += (size_t)NLAYERS * HDIM * HDIM * 2;
    unsigned* cnt = (unsigned*)p;      p += (size_t)N * 4;
    float* dinv = (float*)p;           p += (size_t)N * 4;
    int* rs = (int*)p;                 p += (size_t)(N + 1) * 4 + 12;  // keep 16B align
    unsigned* blocksum = (unsigned*)p; p += 512 * 4;
    int* srcs = (int*)p;               p += (size_t)E * 4;
    float* wwt = (float*)p;            p += (size_t)E * 4;

    const int nb = (N + 255) / 256;                 // 391
    const dim3 ggrid(HDIM / 64, (MPAD / 256));      // (4, 391)

    // ---- Input conversion ----
    wprep_k<<<(FIN * 256 + 255) / 256, 256, 0, stream>>>(w1, w1t, FIN, FIN * 256);
    wprep_k<<<(HDIM * 256 + 255) / 256, 256, 0, stream>>>(w2, w2t, HDIM, HDIM * 256);
    wprep_k<<<(NLAYERS * HDIM * 256 + 255) / 256, 256, 0, stream>>>(gw, gwt, HDIM, NLAYERS * HDIM * 256);
    xconv_k<<<(N * FIN / 4 + 255) / 256, 256, 0, stream>>>(x, xb, N * FIN / 4);

    // ---- CSR build ----
    zero_k<<<nb, 256, 0, stream>>>(cnt, N);
    count_k<<<(E + 255) / 256, 256, 0, stream>>>(dst, cnt, E);
    dinv_k<<<nb, 256, 0, stream>>>(cnt, dinv, N);
    scan1_k<<<nb, 256, 0, stream>>>(cnt, rs, blocksum, N);
    scan2_k<<<1, 512, 0, stream>>>(blocksum, nb);
    scan3_k<<<nb + 1, 256, 0, stream>>>(rs, blocksum, N, E);
    zero_k<<<nb, 256, 0, stream>>>(cnt, N);  // reuse as cursor
    fill_k<<<(E + 255) / 256, 256, 0, stream>>>(src, dst, rs, cnt, dinv, srcs, wwt, E);

    // ---- Encoder ----
    gemm_mfma_k<true, true, false><<<ggrid, 256, 0, stream>>>(xb, w1t, b1, h1, N, FIN);
    gemm_mfma_k<true, false, false><<<ggrid, 256, 0, stream>>>(h1, w2t, b2, h, N, HDIM);

    // ---- GCN layers ----
    for (int l = 0; l < NLAYERS; ++l) {
        const unsigned short* wl = gwt + (size_t)l * HDIM * HDIM;
        const float* bl = gb + (size_t)l * HDIM;
        gemm_mfma_k<false, false, false><<<ggrid, 256, 0, stream>>>(h, wl, nullptr, m, N, HDIM);
        if (l < NLAYERS - 1)
            gather_k<false><<<(N + 3) / 4, 256, 0, stream>>>(rs, srcs, wwt, dinv, m, bl, h, N);
        else
            gather_k<true><<<(N + 3) / 4, 256, 0, stream>>>(rs, srcs, wwt, dinv, m, bl, d_out, N);
    }
}